// Round 2
// baseline (1417.952 us; speedup 1.0000x reference)
//
#include <hip/hip_runtime.h>
#include <stdint.h>

#define NN_NODE 50000
#define NN_EDGE 800000

typedef _Float16 f16;
typedef _Float16 f16x2 __attribute__((ext_vector_type(2)));
typedef _Float16 f16x4 __attribute__((ext_vector_type(4)));
typedef _Float16 f16x8 __attribute__((ext_vector_type(8)));
typedef float f32x4 __attribute__((ext_vector_type(4)));

// ---- workspace layout ----
#define WT_MW0   0        // [256][32]  (K=10 padded to 32)
#define WT_MW1   8192     // [256][256]
#define WT_MW2   73728    // [128][256]
#define WT_AW0   106496   // [128][128]
#define WT_AW1   122880   // [128][128]
#define WT_VW0   139264   // [256][128]
#define WT_VW1   172032   // [128][256]
#define WT_UW0   204800   // [256][128]
#define WT_UW1   237568   // [256][256]
#define WT_TOTAL 303104

#define V_OFF      606208ull                  // f16 v[E][128]   (receiver-sorted)
#define WL_OFF     205406208ull               // float wlog[E]   (receiver-sorted)
#define CNT_OFF    208606208ull               // int cnt/cursor[N]
#define BASE_OFF   208806208ull               // int base[N]
#define AGGR_OFF   209006208ull               // float aggr[N][128]

// XOR-swizzled LDS addressing: rows of 256 f16 = 32 chunks of 8 f16 (16B).
__device__ __forceinline__ int swz(int row, int col) {
    return row * 256 + ((((col >> 3) ^ (row & 7))) << 3) + (col & 7);
}

// ---- fused MLP layer, 16x16x32 MFMA, swapped operands ----
// A = weights W^T[n][k], B = activations from LDS (ds_read_b128).
// D: col=edge=lane&15, row=feature=quad*4+reg.
//
// SINGLE-BUFFER IN-PLACE operation: the compute phase reads all activation
// fragments into registers (each fragment consumed by MFMA before the
// barrier), then IBAR=1 inserts one __syncthreads() (write-after-read fence:
// __syncthreads drains lgkmcnt, so all waves' ds_reads have landed), then the
// epilogue overwrites the same buffer. IBAR=0 for layers whose write region
// is disjoint from the read region (or that don't write LDS at all).
// This halves LDS to 32KB -> 4 blocks/CU = 16 waves (was 2 blocks / 8 waves):
// the kernel is latency-bound (MfmaUtil 20%, VALUBusy 18%, HBM 5%), so
// occupancy is the lever.
//
// bf0: first ct-tile first-half weights, preloaded by the PREVIOUS layer
// (cross-barrier prefetch). KN = next layer's K (row stride for wtn); this
// layer prefetches the NEXT layer's first tile's first half into bfn.
// EPI: 0 = relu -> LDS; 1 = logit partial (dot with aw2, no LDS out);
//      2 = relu -> direct global v-store at spos slot.
template<int K, int N, int KN, int EPI, int IBAR>
__device__ __forceinline__ void mlayer(const f16* in, int inoff,
        const f16* __restrict__ wt, const float* __restrict__ bias,
        f16* out, int outoff,
        f16x8* bf0, const f16* __restrict__ wtn, f16x8* bfn,
        const float* __restrict__ aw2, float* lpart,
        f16* __restrict__ vout, const int* sposp, int tid)
{
    const int wave = tid >> 6;
    const int lane = tid & 63;
    const int l15  = lane & 15;
    const int quad = lane >> 4;
    constexpr int NKS  = K >> 5;                    // total k-slices (1,4,8)
    constexpr int NKH  = (NKS > 4) ? 4 : NKS;       // k-slices per half
    constexpr int NH   = NKS / NKH;                 // 1 or 2 halves
    constexpr int NCT  = N >> 4;
    constexpr int ITC  = NCT / 4;
    constexpr int NKNH = (KN >= 128) ? 4 : (KN >> 5); // next-layer prefetch frags

    f32x4 acc[ITC][4];
#pragma unroll
    for (int i = 0; i < ITC; ++i)
#pragma unroll
        for (int ms = 0; ms < 4; ++ms)
            acc[i][ms] = (f32x4){0.f, 0.f, 0.f, 0.f};

    int sposv[4];
    if constexpr (EPI == 2) {
#pragma unroll
        for (int ms = 0; ms < 4; ++ms) sposv[ms] = sposp[ms * 16 + l15];
    }

    f16x8 bfl[2][NKH];

#pragma unroll
    for (int h = 0; h < NH; ++h) {
        // start-of-half weights for tile ct=wave: h==0 from cross-barrier
        // prefetch; h==1 issue the load first so L2 latency hides under the
        // af LDS reads below.
        if (h == 0) {
#pragma unroll
            for (int ks = 0; ks < NKH; ++ks) bfl[0][ks] = bf0[ks];
        } else {
            const f16* wrow = wt + (size_t)(wave * 16 + l15) * K + h * NKH * 32 + quad * 8;
#pragma unroll
            for (int ks = 0; ks < NKH; ++ks)
                bfl[0][ks] = *(const f16x8*)(wrow + ks * 32);
        }

        // activation fragments for this K-half: load burst, then pin.
        f16x8 af[4][NKH];
#pragma unroll
        for (int ms = 0; ms < 4; ++ms)
#pragma unroll
            for (int ks = 0; ks < NKH; ++ks)
                af[ms][ks] = *(const f16x8*)(in + swz(ms * 16 + l15,
                                    inoff + (h * NKH + ks) * 32 + quad * 8));
        // pin: forbids the compiler from sinking/re-reading these LDS loads
        // inside the ct loop
#pragma unroll
        for (int ms = 0; ms < 4; ++ms)
#pragma unroll
            for (int ks = 0; ks < NKH; ++ks)
                asm volatile("" : "+v"(af[ms][ks]));

        // cross-barrier prefetch of next layer's first tile, first half;
        // issued on the last half so its registers live only half the layer.
        if constexpr (KN > 0) {
            if (h == NH - 1) {
                const f16* wrow = wtn + (size_t)(wave * 16 + l15) * KN + quad * 8;
#pragma unroll
                for (int ks = 0; ks < NKNH; ++ks)
                    bfn[ks] = *(const f16x8*)(wrow + ks * 32);
            }
        }

        // ct-tile loop, in-half weight double-buffer
#pragma unroll
        for (int i = 0; i < ITC; ++i) {
            const int ct = wave + i * 4;
            if (i + 1 < ITC) {
                const f16* wrow2 = wt + (size_t)((ct + 4) * 16 + l15) * K + h * NKH * 32 + quad * 8;
#pragma unroll
                for (int ks = 0; ks < NKH; ++ks)
                    bfl[(i + 1) & 1][ks] = *(const f16x8*)(wrow2 + ks * 32);
            }
#pragma unroll
            for (int ms = 0; ms < 4; ++ms)
#pragma unroll
                for (int ks = 0; ks < NKH; ++ks)
                    acc[i][ms] = __builtin_amdgcn_mfma_f32_16x16x32_f16(
                        bfl[i & 1][ks], af[ms][ks], acc[i][ms], 0, 0, 0);
        }
    }

    // write-after-read fence for in-place update: all waves' af reads have
    // completed (consumed by MFMA; __syncthreads drains lgkmcnt) before any
    // wave overwrites the buffer.
    if constexpr (EPI == 0 && IBAR) __syncthreads();

    // ---- epilogue over all ct tiles ----
    float preg[4];
    if constexpr (EPI == 1) {
#pragma unroll
        for (int ms = 0; ms < 4; ++ms) preg[ms] = 0.f;
    }
#pragma unroll
    for (int i = 0; i < ITC; ++i) {
        const int ct = wave + i * 4;
        const int f0 = ct * 16 + quad * 4;
        const float4 bv = *(const float4*)(bias + f0);
        float4 awv;
        if constexpr (EPI == 1) awv = *(const float4*)(aw2 + f0);
#pragma unroll
        for (int ms = 0; ms < 4; ++ms) {
            if constexpr (EPI == 0) {
                f16x4 o;
                o[0] = (f16)fmaxf(acc[i][ms][0] + bv.x, 0.f);
                o[1] = (f16)fmaxf(acc[i][ms][1] + bv.y, 0.f);
                o[2] = (f16)fmaxf(acc[i][ms][2] + bv.z, 0.f);
                o[3] = (f16)fmaxf(acc[i][ms][3] + bv.w, 0.f);
                *(f16x4*)(out + swz(ms * 16 + l15, outoff + f0)) = o;
            } else if constexpr (EPI == 1) {
                preg[ms] += fmaxf(acc[i][ms][0] + bv.x, 0.f) * awv.x
                          + fmaxf(acc[i][ms][1] + bv.y, 0.f) * awv.y
                          + fmaxf(acc[i][ms][2] + bv.z, 0.f) * awv.z
                          + fmaxf(acc[i][ms][3] + bv.w, 0.f) * awv.w;
            } else {
                f16x4 o;
                o[0] = (f16)fmaxf(acc[i][ms][0] + bv.x, 0.f);
                o[1] = (f16)fmaxf(acc[i][ms][1] + bv.y, 0.f);
                o[2] = (f16)fmaxf(acc[i][ms][2] + bv.z, 0.f);
                o[3] = (f16)fmaxf(acc[i][ms][3] + bv.w, 0.f);
                *(f16x4*)(vout + (size_t)sposv[ms] * 128 + f0) = o;
            }
        }
    }
    if constexpr (EPI == 1) {
#pragma unroll
        for (int ms = 0; ms < 4; ++ms) {
            float r = preg[ms];
            r += __shfl_xor(r, 16);
            r += __shfl_xor(r, 32);
            if (quad == 0) lpart[wave * 64 + ms * 16 + l15] = r;
        }
    }
}

// ---- simple layer variant (node_kernel) ----
template<int K, int N>
__device__ __forceinline__ void mfma_layer_basic(const f16* in, int inoff,
        const f16* __restrict__ wt, const float* __restrict__ bias,
        f16* out, int outoff, int tid)
{
    const int wave = tid >> 6;
    const int lane = tid & 63;
    const int l15  = lane & 15;
    const int quad = lane >> 4;
    constexpr int NCT = N >> 4;
    constexpr int NKS = K >> 5;
    f16x8 af[4][NKS];
#pragma unroll
    for (int ms = 0; ms < 4; ++ms)
#pragma unroll
        for (int ks = 0; ks < NKS; ++ks)
            af[ms][ks] = *(const f16x8*)(in + swz(ms * 16 + l15, inoff + ks * 32 + quad * 8));
#pragma unroll 1
    for (int ct = wave; ct < NCT; ct += 4) {
        f16x8 bf[NKS];
        const f16* wrow = wt + (size_t)(ct * 16 + l15) * K + quad * 8;
#pragma unroll
        for (int ks = 0; ks < NKS; ++ks) bf[ks] = *(const f16x8*)(wrow + ks * 32);
        const int f0 = ct * 16 + quad * 4;
        const float4 bv = *(const float4*)(bias + f0);
#pragma unroll
        for (int ms = 0; ms < 4; ++ms) {
            f32x4 acc = {0.f, 0.f, 0.f, 0.f};
#pragma unroll
            for (int ks = 0; ks < NKS; ++ks)
                acc = __builtin_amdgcn_mfma_f32_16x16x32_f16(bf[ks], af[ms][ks], acc, 0, 0, 0);
            f16x4 o;
            o[0] = (f16)fmaxf(acc[0] + bv.x, 0.f);
            o[1] = (f16)fmaxf(acc[1] + bv.y, 0.f);
            o[2] = (f16)fmaxf(acc[2] + bv.z, 0.f);
            o[3] = (f16)fmaxf(acc[3] + bv.w, 0.f);
            *(f16x4*)(out + swz(ms * 16 + l15, outoff + f0)) = o;
        }
    }
}

// ---- prep: transpose-convert weights to f16 [N][Kpad] ----
struct WSeg { const float* src; int K, N, Kpad, dstOff; };
struct WSegs { WSeg s[9]; };

__global__ void prep_kernel(WSegs segs, f16* __restrict__ wt) {
    int idx = blockIdx.x * 256 + threadIdx.x;
    if (idx >= WT_TOTAL) return;
    int off = idx;
#pragma unroll
    for (int i = 0; i < 9; ++i) {
        int sz = segs.s[i].N * segs.s[i].Kpad;
        if (off < sz) {
            int n = off / segs.s[i].Kpad;
            int k = off - n * segs.s[i].Kpad;
            f16 val = (f16)0.f;
            if (k < segs.s[i].K) val = (f16)segs.s[i].src[k * segs.s[i].N + n];
            wt[segs.s[i].dstOff + off] = val;
            return;
        }
        off -= sz;
    }
}

// ---- sort step 1: histogram of receivers ----
__global__ void hist_kernel(const int* __restrict__ receivers, int* __restrict__ cnt) {
    int e = blockIdx.x * 256 + threadIdx.x;
    atomicAdd(&cnt[receivers[e]], 1);
}

// ---- sort step 2: exclusive scan ----
__global__ __launch_bounds__(1024) void scan_kernel(int* __restrict__ cnt, int* __restrict__ base) {
    __shared__ int psum[1024];
    const int tid = threadIdx.x;
    const int CH = (NN_NODE + 1023) / 1024;
    const int lo = tid * CH;
    const int hi = min(lo + CH, NN_NODE);
    int s = 0;
    for (int i = lo; i < hi; ++i) s += cnt[i];
    psum[tid] = s;
    __syncthreads();
    for (int d = 1; d < 1024; d <<= 1) {
        int v = (tid >= d) ? psum[tid - d] : 0;
        __syncthreads();
        psum[tid] += v;
        __syncthreads();
    }
    int run = psum[tid] - s;
    for (int i = lo; i < hi; ++i) {
        int c = cnt[i];
        base[i] = run;
        cnt[i] = run;
        run += c;
    }
}

// ---- K1: per-edge encoder + attention logit + value; 64 edges/block ----
// Single 32KB LDS buffer (in-place layers) -> 4 blocks/CU, 16 waves/CU.
// Buffer column map: z cols 0-31; a1/a2 cols 0-255; q cols 0-127;
// h0 cols 128-255 (disjoint from q -> AW0 needs no internal barrier);
// v1 cols 0-255.
__global__ __launch_bounds__(256, 4) void edge_kernel(
        const float* __restrict__ nodes, const float* __restrict__ edges,
        const int* __restrict__ senders, const int* __restrict__ receivers,
        const f16* __restrict__ wt,
        const float* __restrict__ mb0, const float* __restrict__ mb1, const float* __restrict__ mb2,
        const float* __restrict__ ab0, const float* __restrict__ ab1,
        const float* __restrict__ aw2, const float* __restrict__ ab2,
        const float* __restrict__ vb0, const float* __restrict__ vb1,
        f16* __restrict__ vout, float* __restrict__ wlog, int* __restrict__ cursor)
{
    __shared__ f16 buf[64 * 256];   // 32 KB
    __shared__ int spos[64];
    __shared__ float lpart[256];
    const int tid = threadIdx.x;
    const int e0 = blockIdx.x * 64;
    const int wave = tid >> 6;
    const int lane = tid & 63;
    const int l15  = lane & 15;
    const int quad = lane >> 4;

    f16x8 bfA[4], bfB[4];

    // preload L1's first weight tile (cross-barrier prefetch seed; NKS=1)
    {
        const f16* wrow = wt + WT_MW0 + (size_t)(wave * 16 + l15) * 32 + quad * 8;
        bfA[0] = *(const f16x8*)wrow;
    }

    // stage z: one b128 write per thread. Thread (e, c) owns chunk c of row e.
    // chunk0 = [s.xyz, r.xyz, edge01], chunk1 = [edge23, 0...], chunk2/3 = 0.
    {
        const int e = tid & 63, c = tid >> 6;
        f16x8 zv = {(f16)0.f,(f16)0.f,(f16)0.f,(f16)0.f,(f16)0.f,(f16)0.f,(f16)0.f,(f16)0.f};
        if (c == 0) {
            int s = senders[e0 + e];
            int r = receivers[e0 + e];
            const float2 ev = *(const float2*)(edges + (size_t)(e0 + e) * 4);
            zv[0] = (f16)nodes[s * 3 + 0]; zv[1] = (f16)nodes[s * 3 + 1]; zv[2] = (f16)nodes[s * 3 + 2];
            zv[3] = (f16)nodes[r * 3 + 0]; zv[4] = (f16)nodes[r * 3 + 1]; zv[5] = (f16)nodes[r * 3 + 2];
            zv[6] = (f16)ev.x; zv[7] = (f16)ev.y;
        } else if (c == 1) {
            const float2 ev = *(const float2*)(edges + (size_t)(e0 + e) * 4 + 2);
            zv[0] = (f16)ev.x; zv[1] = (f16)ev.y;
        }
        *(f16x8*)(buf + e * 256 + ((c ^ (e & 7)) << 3)) = zv;
    }
    __syncthreads();

    mlayer< 32, 256, 256, 0, 1>(buf, 0, wt + WT_MW0, mb0, buf, 0, bfA, wt + WT_MW1, bfB,
                                nullptr, nullptr, nullptr, nullptr, tid);
    __syncthreads();
    mlayer<256, 256, 256, 0, 1>(buf, 0, wt + WT_MW1, mb1, buf, 0, bfB, wt + WT_MW2, bfA,
                                nullptr, nullptr, nullptr, nullptr, tid);
    __syncthreads();
    mlayer<256, 128, 128, 0, 1>(buf, 0, wt + WT_MW2, mb2, buf, 0, bfA, wt + WT_AW0, bfB,
                                nullptr, nullptr, nullptr, nullptr, tid);   // q in cols 0-127
    __syncthreads();
    mlayer<128, 128, 128, 0, 0>(buf, 0, wt + WT_AW0, ab0, buf, 128, bfB, wt + WT_AW1, bfA,
                                nullptr, nullptr, nullptr, nullptr, tid);   // h0 in cols 128-255
    __syncthreads();
    mlayer<128, 128, 128, 1, 0>(buf, 128, wt + WT_AW1, ab1, nullptr, 0, bfA, wt + WT_VW0, bfB,
                                aw2, lpart, nullptr, nullptr, tid);         // logit partials
    __syncthreads();

    // finalize logits (wave 0) while other waves run VW0's compute phase
    if (tid < 64) {
        float wv = lpart[tid] + lpart[64 + tid] + lpart[128 + tid] + lpart[192 + tid] + ab2[0];
        int r = receivers[e0 + tid];
        int pos = atomicAdd(&cursor[r], 1);
        spos[tid] = pos;
        wlog[pos] = wv;
    }
    mlayer<128, 256, 256, 0, 1>(buf, 0, wt + WT_VW0, vb0, buf, 0, bfB, wt + WT_VW1, bfA,
                                nullptr, nullptr, nullptr, nullptr, tid);   // v1 in cols 0-255
    __syncthreads();
    mlayer<256, 128, 0, 2, 0>(buf, 0, wt + WT_VW1, vb1, nullptr, 0, bfA, nullptr, nullptr,
                              nullptr, nullptr, vout, spos, tid);           // v direct to global
}

// ---- K2: per-node segmented softmax + weighted aggregation (1 wave / node) ----
__global__ __launch_bounds__(256) void aggregate_kernel(
        const float* __restrict__ wlog, const f16* __restrict__ v,
        const int* __restrict__ base, float* __restrict__ aggr)
{
    const int tid = threadIdx.x;
    const int n = blockIdx.x * 4 + (tid >> 6);
    const int lane = tid & 63;
    const int st = base[n];
    const int en = (n == NN_NODE - 1) ? NN_EDGE : base[n + 1];

    float mx = -1e9f;
    for (int i = st + lane; i < en; i += 64) mx = fmaxf(mx, wlog[i]);
#pragma unroll
    for (int d = 1; d < 64; d <<= 1) mx = fmaxf(mx, __shfl_xor(mx, d));

    float sm = 0.f;
    for (int i = st + lane; i < en; i += 64) sm += __expf(wlog[i] - mx);
#pragma unroll
    for (int d = 1; d < 64; d <<= 1) sm += __shfl_xor(sm, d);
    const float inv = 1.f / (sm + 1e-12f);

    float acc0 = 0.f, acc1 = 0.f;
    const f16* vp = v + (size_t)st * 128 + lane * 2;
    for (int i = st; i < en; ++i, vp += 128) {
        float attn = __expf(wlog[i] - mx) * inv;
        f16x2 vv = *(const f16x2*)vp;
        acc0 += attn * (float)vv[0];
        acc1 += attn * (float)vv[1];
    }
    float2 o; o.x = acc0; o.y = acc1;
    *(float2*)(aggr + (size_t)n * 128 + lane * 2) = o;
}

// ---- K3: node decoder (64-node tiles) ----
__global__ __launch_bounds__(256, 2) void node_kernel(
        const float* __restrict__ aggr, const f16* __restrict__ wt,
        const float* __restrict__ ub0, const float* __restrict__ ub1,
        const float* __restrict__ uw2, const float* __restrict__ ub2,
        float* __restrict__ out)
{
    __shared__ f16 ldsbuf[2 * 64 * 256];
    f16* bufA = ldsbuf;
    f16* bufB = ldsbuf + 64 * 256;
    const int tid = threadIdx.x;
    const int n0 = blockIdx.x * 64;
    {
        int row = tid >> 2, j = tid & 3;
        int n = n0 + row;
        if (n < NN_NODE) {
            const float4* src = (const float4*)(aggr + (size_t)n * 128 + j * 32);
#pragma unroll
            for (int i = 0; i < 8; ++i) {
                float4 t4 = src[i];
                int c = j * 32 + i * 4;
                bufA[swz(row, c + 0)] = (f16)t4.x;
                bufA[swz(row, c + 1)] = (f16)t4.y;
                bufA[swz(row, c + 2)] = (f16)t4.z;
                bufA[swz(row, c + 3)] = (f16)t4.w;
            }
        } else {
#pragma unroll
            for (int i = 0; i < 32; ++i) bufA[swz(row, j * 32 + i)] = (f16)0.f;
        }
    }
    __syncthreads();
    mfma_layer_basic<128, 256>(bufA, 0, wt + WT_UW0, ub0, bufB, 0, tid); __syncthreads();
    mfma_layer_basic<256, 256>(bufB, 0, wt + WT_UW1, ub1, bufA, 0, tid); __syncthreads();
    {
        int e = tid >> 2, part = tid & 3;
        float sum = 0.f;
        for (int c = part * 64; c < part * 64 + 64; ++c)
            sum += (float)bufA[swz(e, c)] * uw2[c];
        sum += __shfl_down(sum, 2);
        sum += __shfl_down(sum, 1);
        int n = n0 + e;
        if (part == 0 && n < NN_NODE) out[n] = sum + ub2[0];
    }
}

extern "C" void kernel_launch(void* const* d_in, const int* in_sizes, int n_in,
                              void* d_out, int out_size, void* d_ws, size_t ws_size,
                              hipStream_t stream)
{
    const float* nodes     = (const float*)d_in[0];
    const float* edges     = (const float*)d_in[1];
    const int*   senders   = (const int*)d_in[2];
    const int*   receivers = (const int*)d_in[3];
    const float* mw0 = (const float*)d_in[4];  const float* mb0 = (const float*)d_in[5];
    const float* mw1 = (const float*)d_in[6];  const float* mb1 = (const float*)d_in[7];
    const float* mw2 = (const float*)d_in[8];  const float* mb2 = (const float*)d_in[9];
    const float* aw0 = (const float*)d_in[10]; const float* ab0 = (const float*)d_in[11];
    const float* aw1 = (const float*)d_in[12]; const float* ab1 = (const float*)d_in[13];
    const float* aw2 = (const float*)d_in[14]; const float* ab2 = (const float*)d_in[15];
    const float* vw0 = (const float*)d_in[16]; const float* vb0 = (const float*)d_in[17];
    const float* vw1 = (const float*)d_in[18]; const float* vb1 = (const float*)d_in[19];
    const float* uw0 = (const float*)d_in[20]; const float* ub0 = (const float*)d_in[21];
    const float* uw1 = (const float*)d_in[22]; const float* ub1 = (const float*)d_in[23];
    const float* uw2 = (const float*)d_in[24]; const float* ub2 = (const float*)d_in[25];

    char* ws = (char*)d_ws;
    f16*   wt   = (f16*)ws;
    f16*   vbuf = (f16*)(ws + V_OFF);
    float* wlog = (float*)(ws + WL_OFF);
    int*   cnt  = (int*)(ws + CNT_OFF);
    int*   base = (int*)(ws + BASE_OFF);
    float* aggr = (float*)(ws + AGGR_OFF);
    float* out  = (float*)d_out;

    hipMemsetAsync(cnt, 0, NN_NODE * sizeof(int), stream);

    WSegs segs = {{
        { mw0,  10, 256,  32, WT_MW0 },
        { mw1, 256, 256, 256, WT_MW1 },
        { mw2, 256, 128, 256, WT_MW2 },
        { aw0, 128, 128, 128, WT_AW0 },
        { aw1, 128, 128, 128, WT_AW1 },
        { vw0, 128, 256, 128, WT_VW0 },
        { vw1, 256, 128, 256, WT_VW1 },
        { uw0, 128, 256, 128, WT_UW0 },
        { uw1, 256, 256, 256, WT_UW1 },
    }};
    prep_kernel<<<(WT_TOTAL + 255) / 256, 256, 0, stream>>>(segs, wt);

    hist_kernel<<<NN_EDGE / 256, 256, 0, stream>>>(receivers, cnt);
    scan_kernel<<<1, 1024, 0, stream>>>(cnt, base);

    edge_kernel<<<NN_EDGE / 64, 256, 0, stream>>>(nodes, edges, senders, receivers, wt,
        mb0, mb1, mb2, ab0, ab1, aw2, ab2, vb0, vb1, vbuf, wlog, cnt);

    aggregate_kernel<<<NN_NODE / 4, 256, 0, stream>>>(wlog, vbuf, base, aggr);

    node_kernel<<<(NN_NODE + 63) / 64, 256, 0, stream>>>(aggr, wt, ub0, ub1, uw2, ub2, out);
}

// Round 3
// 969.908 us; speedup vs baseline: 1.4619x; 1.4619x over previous
//
#include <hip/hip_runtime.h>
#include <stdint.h>

#define NN_NODE 50000
#define NN_EDGE 800000

typedef _Float16 f16;
typedef _Float16 f16x2 __attribute__((ext_vector_type(2)));
typedef _Float16 f16x4 __attribute__((ext_vector_type(4)));
typedef _Float16 f16x8 __attribute__((ext_vector_type(8)));
typedef float f32x4 __attribute__((ext_vector_type(4)));

// ---- workspace layout ----
#define WT_MW0   0        // [256][32]  (K=10 padded to 32)
#define WT_MW1   8192     // [256][256]
#define WT_MW2   73728    // [128][256]
#define WT_AW0   106496   // [128][128]
#define WT_AW1   122880   // [128][128]
#define WT_VW0   139264   // [256][128]
#define WT_VW1   172032   // [128][256]
#define WT_UW0   204800   // [256][128]
#define WT_UW1   237568   // [256][256]
#define WT_TOTAL 303104

#define V_OFF      606208ull                  // f16 v[E][128]   (receiver-sorted)
#define WL_OFF     205406208ull               // float wlog[E]   (receiver-sorted)
#define CNT_OFF    208606208ull               // int cnt/cursor[N]
#define BASE_OFF   208806208ull               // int base[N]
#define AGGR_OFF   209006208ull               // float aggr[N][128]

// XOR-swizzled LDS addressing: rows of 256 f16 = 32 chunks of 8 f16 (16B).
__device__ __forceinline__ int swz(int row, int col) {
    return row * 256 + ((((col >> 3) ^ (row & 7))) << 3) + (col & 7);
}

// ---- fused MLP layer, 16x16x32 MFMA, swapped operands ----
// A = weights W^T[n][k], B = activations from LDS (ds_read_b128).
// D: col=edge=lane&15, row=feature=quad*4+reg.
//
// Weight tiles are flattened into one sequence s = h*ITC + i (h = K-half,
// i = ct-tile index) and streamed through a 3-deep register pipeline
// bfl[3][NKH]: tile s+3 is issued right AFTER the MFMAs of tile s (the slot
// (s+3)%3 == s%3 is recycled), giving ~2 full iterations (~310+ cyc with 2
// co-resident waves/SIMD) of issue-to-use distance -- enough to cover L1/L2
// weight-load latency. R1's 1-deep prefetch gave only ~156 cyc => per-iter
// vmcnt stalls => MfmaUtil 20%.
//
// Cross-barrier prefetch carries the FIRST TWO tiles of the next layer
// (bfn[2][4], filled during the last 2 loop iterations); K=128 layers
// (NT=2) therefore need zero in-layer weight loads.
//
// EPI: 0 = relu -> LDS; 1 = logit partial (dot with aw2, no LDS out);
//      2 = relu -> direct global v-store at spos slot.
template<int K, int N, int KN, int EPI>
__device__ __forceinline__ void mlayer(const f16* in, int inoff,
        const f16* __restrict__ wt, const float* __restrict__ bias,
        f16* out, int outoff,
        f16x8 (&bf0)[2][4], const f16* __restrict__ wtn, f16x8 (&bfn)[2][4],
        const float* __restrict__ aw2, float* lpart,
        f16* __restrict__ vout, const int* sposp, int tid)
{
    const int wave = tid >> 6;
    const int lane = tid & 63;
    const int l15  = lane & 15;
    const int quad = lane >> 4;
    constexpr int NKS  = K >> 5;                    // total k-slices (1,4,8)
    constexpr int NKH  = (NKS > 4) ? 4 : NKS;       // k-slices per half
    constexpr int NH   = NKS / NKH;                 // 1 or 2 halves
    constexpr int NCT  = N >> 4;
    constexpr int ITC  = NCT / 4;                   // ct tiles per wave
    constexpr int NT   = NH * ITC;                  // total weight tiles (2..8)
    constexpr int PD   = (NT >= 3) ? 3 : 2;         // pipeline depth
    constexpr int NKNH = (KN >= 128) ? 4 : (KN >> 5); // next-layer frag count

    f32x4 acc[ITC][4];
#pragma unroll
    for (int i = 0; i < ITC; ++i)
#pragma unroll
        for (int ms = 0; ms < 4; ++ms)
            acc[i][ms] = (f32x4){0.f, 0.f, 0.f, 0.f};

    int sposv[4];
    if constexpr (EPI == 2) {
#pragma unroll
        for (int ms = 0; ms < 4; ++ms) sposv[ms] = sposp[ms * 16 + l15];
    }

    f16x8 af[4][NKH];
    f16x8 bfl[3][NKH];

    // ---- prologue: slots 0,1 from cross-barrier prefetch; issue tile 2 ----
#pragma unroll
    for (int ks = 0; ks < NKH; ++ks) bfl[0][ks] = bf0[0][ks];
#pragma unroll
    for (int ks = 0; ks < NKH; ++ks) bfl[1][ks] = bf0[1][ks];
    if constexpr (NT > 2) {
        constexpr int h2 = 2 / ITC, i2 = 2 % ITC;
        const f16* w2 = wt + (size_t)((wave + i2 * 4) * 16 + l15) * K + h2 * NKH * 32 + quad * 8;
#pragma unroll
        for (int ks = 0; ks < NKH; ++ks) bfl[2][ks] = *(const f16x8*)(w2 + ks * 32);
    }

    // activation fragments for K-half 0: load burst, then pin (forbids the
    // compiler from sinking/re-reading these LDS loads inside the tile loop)
#pragma unroll
    for (int ms = 0; ms < 4; ++ms)
#pragma unroll
        for (int ks = 0; ks < NKH; ++ks)
            af[ms][ks] = *(const f16x8*)(in + swz(ms * 16 + l15,
                                inoff + ks * 32 + quad * 8));
#pragma unroll
    for (int ms = 0; ms < 4; ++ms)
#pragma unroll
        for (int ks = 0; ks < NKH; ++ks)
            asm volatile("" : "+v"(af[ms][ks]));

    // ---- main tile loop ----
#pragma unroll
    for (int s = 0; s < NT; ++s) {
        const int is = s % ITC;
        // reload af at the K-half boundary (once per K=256 layer; ~120cyc)
        if (NH == 2 && s == ITC) {
#pragma unroll
            for (int ms = 0; ms < 4; ++ms)
#pragma unroll
                for (int ks = 0; ks < NKH; ++ks)
                    af[ms][ks] = *(const f16x8*)(in + swz(ms * 16 + l15,
                                        inoff + (NKH + ks) * 32 + quad * 8));
#pragma unroll
            for (int ms = 0; ms < 4; ++ms)
#pragma unroll
                for (int ks = 0; ks < NKH; ++ks)
                    asm volatile("" : "+v"(af[ms][ks]));
        }
        // MFMAs for tile s (slot s%3)
#pragma unroll
        for (int ms = 0; ms < 4; ++ms)
#pragma unroll
            for (int ks = 0; ks < NKH; ++ks)
                acc[is][ms] = __builtin_amdgcn_mfma_f32_16x16x32_f16(
                    bfl[s % 3][ks], af[ms][ks], acc[is][ms], 0, 0, 0);
        // recycle the just-consumed slot: issue tile s+PD (or next layer's
        // first two tiles via bfn). Issued AFTER the consuming MFMAs --
        // issuing before would overwrite the live tile (slot (s+3)%3==s%3).
        if (s + PD < NT) {
            const int t = s + PD, ht = t / ITC, it = t % ITC;
            const f16* wr = wt + (size_t)((wave + it * 4) * 16 + l15) * K + ht * NKH * 32 + quad * 8;
#pragma unroll
            for (int ks = 0; ks < NKH; ++ks)
                bfl[t % 3][ks] = *(const f16x8*)(wr + ks * 32);
        } else if constexpr (KN > 0) {
            const int j = s + PD - NT;
            if (j < 2) {
                const f16* wr = wtn + (size_t)((wave + j * 4) * 16 + l15) * KN + quad * 8;
#pragma unroll
                for (int ks = 0; ks < NKNH; ++ks)
                    bfn[j][ks] = *(const f16x8*)(wr + ks * 32);
            }
        }
    }

    // ---- epilogue over all ct tiles ----
    float preg[4];
    if constexpr (EPI == 1) {
#pragma unroll
        for (int ms = 0; ms < 4; ++ms) preg[ms] = 0.f;
    }
#pragma unroll
    for (int i = 0; i < ITC; ++i) {
        const int ct = wave + i * 4;
        const int f0 = ct * 16 + quad * 4;
        const float4 bv = *(const float4*)(bias + f0);
        float4 awv;
        if constexpr (EPI == 1) awv = *(const float4*)(aw2 + f0);
#pragma unroll
        for (int ms = 0; ms < 4; ++ms) {
            if constexpr (EPI == 0) {
                f16x4 o;
                o[0] = (f16)fmaxf(acc[i][ms][0] + bv.x, 0.f);
                o[1] = (f16)fmaxf(acc[i][ms][1] + bv.y, 0.f);
                o[2] = (f16)fmaxf(acc[i][ms][2] + bv.z, 0.f);
                o[3] = (f16)fmaxf(acc[i][ms][3] + bv.w, 0.f);
                *(f16x4*)(out + swz(ms * 16 + l15, outoff + f0)) = o;
            } else if constexpr (EPI == 1) {
                preg[ms] += fmaxf(acc[i][ms][0] + bv.x, 0.f) * awv.x
                          + fmaxf(acc[i][ms][1] + bv.y, 0.f) * awv.y
                          + fmaxf(acc[i][ms][2] + bv.z, 0.f) * awv.z
                          + fmaxf(acc[i][ms][3] + bv.w, 0.f) * awv.w;
            } else {
                f16x4 o;
                o[0] = (f16)fmaxf(acc[i][ms][0] + bv.x, 0.f);
                o[1] = (f16)fmaxf(acc[i][ms][1] + bv.y, 0.f);
                o[2] = (f16)fmaxf(acc[i][ms][2] + bv.z, 0.f);
                o[3] = (f16)fmaxf(acc[i][ms][3] + bv.w, 0.f);
                *(f16x4*)(vout + (size_t)sposv[ms] * 128 + f0) = o;
            }
        }
    }
    if constexpr (EPI == 1) {
#pragma unroll
        for (int ms = 0; ms < 4; ++ms) {
            float r = preg[ms];
            r += __shfl_xor(r, 16);
            r += __shfl_xor(r, 32);
            if (quad == 0) lpart[wave * 64 + ms * 16 + l15] = r;
        }
    }
}

// ---- simple layer variant (node_kernel) ----
template<int K, int N>
__device__ __forceinline__ void mfma_layer_basic(const f16* in, int inoff,
        const f16* __restrict__ wt, const float* __restrict__ bias,
        f16* out, int outoff, int tid)
{
    const int wave = tid >> 6;
    const int lane = tid & 63;
    const int l15  = lane & 15;
    const int quad = lane >> 4;
    constexpr int NCT = N >> 4;
    constexpr int NKS = K >> 5;
    f16x8 af[4][NKS];
#pragma unroll
    for (int ms = 0; ms < 4; ++ms)
#pragma unroll
        for (int ks = 0; ks < NKS; ++ks)
            af[ms][ks] = *(const f16x8*)(in + swz(ms * 16 + l15, inoff + ks * 32 + quad * 8));
#pragma unroll 1
    for (int ct = wave; ct < NCT; ct += 4) {
        f16x8 bf[NKS];
        const f16* wrow = wt + (size_t)(ct * 16 + l15) * K + quad * 8;
#pragma unroll
        for (int ks = 0; ks < NKS; ++ks) bf[ks] = *(const f16x8*)(wrow + ks * 32);
        const int f0 = ct * 16 + quad * 4;
        const float4 bv = *(const float4*)(bias + f0);
#pragma unroll
        for (int ms = 0; ms < 4; ++ms) {
            f32x4 acc = {0.f, 0.f, 0.f, 0.f};
#pragma unroll
            for (int ks = 0; ks < NKS; ++ks)
                acc = __builtin_amdgcn_mfma_f32_16x16x32_f16(bf[ks], af[ms][ks], acc, 0, 0, 0);
            f16x4 o;
            o[0] = (f16)fmaxf(acc[0] + bv.x, 0.f);
            o[1] = (f16)fmaxf(acc[1] + bv.y, 0.f);
            o[2] = (f16)fmaxf(acc[2] + bv.z, 0.f);
            o[3] = (f16)fmaxf(acc[3] + bv.w, 0.f);
            *(f16x4*)(out + swz(ms * 16 + l15, outoff + f0)) = o;
        }
    }
}

// ---- prep: transpose-convert weights to f16 [N][Kpad] ----
struct WSeg { const float* src; int K, N, Kpad, dstOff; };
struct WSegs { WSeg s[9]; };

__global__ void prep_kernel(WSegs segs, f16* __restrict__ wt) {
    int idx = blockIdx.x * 256 + threadIdx.x;
    if (idx >= WT_TOTAL) return;
    int off = idx;
#pragma unroll
    for (int i = 0; i < 9; ++i) {
        int sz = segs.s[i].N * segs.s[i].Kpad;
        if (off < sz) {
            int n = off / segs.s[i].Kpad;
            int k = off - n * segs.s[i].Kpad;
            f16 val = (f16)0.f;
            if (k < segs.s[i].K) val = (f16)segs.s[i].src[k * segs.s[i].N + n];
            wt[segs.s[i].dstOff + off] = val;
            return;
        }
        off -= sz;
    }
}

// ---- sort step 1: histogram of receivers ----
__global__ void hist_kernel(const int* __restrict__ receivers, int* __restrict__ cnt) {
    int e = blockIdx.x * 256 + threadIdx.x;
    atomicAdd(&cnt[receivers[e]], 1);
}

// ---- sort step 2: exclusive scan ----
__global__ __launch_bounds__(1024) void scan_kernel(int* __restrict__ cnt, int* __restrict__ base) {
    __shared__ int psum[1024];
    const int tid = threadIdx.x;
    const int CH = (NN_NODE + 1023) / 1024;
    const int lo = tid * CH;
    const int hi = min(lo + CH, NN_NODE);
    int s = 0;
    for (int i = lo; i < hi; ++i) s += cnt[i];
    psum[tid] = s;
    __syncthreads();
    for (int d = 1; d < 1024; d <<= 1) {
        int v = (tid >= d) ? psum[tid - d] : 0;
        __syncthreads();
        psum[tid] += v;
        __syncthreads();
    }
    int run = psum[tid] - s;
    for (int i = lo; i < hi; ++i) {
        int c = cnt[i];
        base[i] = run;
        cnt[i] = run;
        run += c;
    }
}

// ---- K1: per-edge encoder + attention logit + value; 64 edges/block ----
// Double-buffered 64KB LDS, 2 blocks/CU (R1 structure; 4 blocks/CU spills).
__global__ __launch_bounds__(256, 2) void edge_kernel(
        const float* __restrict__ nodes, const float* __restrict__ edges,
        const int* __restrict__ senders, const int* __restrict__ receivers,
        const f16* __restrict__ wt,
        const float* __restrict__ mb0, const float* __restrict__ mb1, const float* __restrict__ mb2,
        const float* __restrict__ ab0, const float* __restrict__ ab1,
        const float* __restrict__ aw2, const float* __restrict__ ab2,
        const float* __restrict__ vb0, const float* __restrict__ vb1,
        f16* __restrict__ vout, float* __restrict__ wlog, int* __restrict__ cursor)
{
    __shared__ f16 ldsbuf[2 * 64 * 256];   // 64 KB
    __shared__ int spos[64];
    __shared__ float lpart[256];
    f16* bufA = ldsbuf;
    f16* bufB = ldsbuf + 64 * 256;
    const int tid = threadIdx.x;
    const int e0 = blockIdx.x * 64;
    const int wave = tid >> 6;
    const int lane = tid & 63;
    const int l15  = lane & 15;
    const int quad = lane >> 4;

    f16x8 bfA[2][4], bfB[2][4];

    // preload L1's first two weight tiles (cross-barrier prefetch seed;
    // L1 has NKH=1, tiles ct=wave and ct=wave+4, K-stride 32)
    {
        const f16* wrow = wt + WT_MW0 + (size_t)(wave * 16 + l15) * 32 + quad * 8;
        bfA[0][0] = *(const f16x8*)wrow;
        bfA[1][0] = *(const f16x8*)(wrow + 64 * 32);
    }

    // stage z: one b128 write per thread. Thread (e, c) owns chunk c of row e.
    // chunk0 = [s.xyz, r.xyz, edge01], chunk1 = [edge23, 0...], chunk2/3 = 0.
    {
        const int e = tid & 63, c = tid >> 6;
        f16x8 zv = {(f16)0.f,(f16)0.f,(f16)0.f,(f16)0.f,(f16)0.f,(f16)0.f,(f16)0.f,(f16)0.f};
        if (c == 0) {
            int s = senders[e0 + e];
            int r = receivers[e0 + e];
            const float2 ev = *(const float2*)(edges + (size_t)(e0 + e) * 4);
            zv[0] = (f16)nodes[s * 3 + 0]; zv[1] = (f16)nodes[s * 3 + 1]; zv[2] = (f16)nodes[s * 3 + 2];
            zv[3] = (f16)nodes[r * 3 + 0]; zv[4] = (f16)nodes[r * 3 + 1]; zv[5] = (f16)nodes[r * 3 + 2];
            zv[6] = (f16)ev.x; zv[7] = (f16)ev.y;
        } else if (c == 1) {
            const float2 ev = *(const float2*)(edges + (size_t)(e0 + e) * 4 + 2);
            zv[0] = (f16)ev.x; zv[1] = (f16)ev.y;
        }
        *(f16x8*)(bufA + e * 256 + ((c ^ (e & 7)) << 3)) = zv;
    }
    __syncthreads();

    mlayer< 32, 256, 256, 0>(bufA, 0, wt + WT_MW0, mb0, bufB, 0, bfA, wt + WT_MW1, bfB,
                             nullptr, nullptr, nullptr, nullptr, tid);
    __syncthreads();
    mlayer<256, 256, 256, 0>(bufB, 0, wt + WT_MW1, mb1, bufA, 0, bfB, wt + WT_MW2, bfA,
                             nullptr, nullptr, nullptr, nullptr, tid);
    __syncthreads();
    mlayer<256, 128, 128, 0>(bufA, 0, wt + WT_MW2, mb2, bufB, 0, bfA, wt + WT_AW0, bfB,
                             nullptr, nullptr, nullptr, nullptr, tid);   // q in bufB
    __syncthreads();
    mlayer<128, 128, 128, 0>(bufB, 0, wt + WT_AW0, ab0, bufA, 0, bfB, wt + WT_AW1, bfA,
                             nullptr, nullptr, nullptr, nullptr, tid);   // h0 in bufA
    __syncthreads();
    mlayer<128, 128, 128, 1>(bufA, 0, wt + WT_AW1, ab1, nullptr, 0, bfA, wt + WT_VW0, bfB,
                             aw2, lpart, nullptr, nullptr, tid);         // logit partials
    __syncthreads();

    // finalize logits (wave 0) while other waves run VW0
    if (tid < 64) {
        float wv = lpart[tid] + lpart[64 + tid] + lpart[128 + tid] + lpart[192 + tid] + ab2[0];
        int r = receivers[e0 + tid];
        int pos = atomicAdd(&cursor[r], 1);
        spos[tid] = pos;
        wlog[pos] = wv;
    }
    mlayer<128, 256, 256, 0>(bufB, 0, wt + WT_VW0, vb0, bufA, 0, bfB, wt + WT_VW1, bfA,
                             nullptr, nullptr, nullptr, nullptr, tid);
    __syncthreads();
    mlayer<256, 128, 0, 2>(bufA, 0, wt + WT_VW1, vb1, nullptr, 0, bfA, nullptr, bfB,
                           nullptr, nullptr, vout, spos, tid);           // v direct to global
}

// ---- K2: per-node segmented softmax + weighted aggregation (1 wave / node) ----
__global__ __launch_bounds__(256) void aggregate_kernel(
        const float* __restrict__ wlog, const f16* __restrict__ v,
        const int* __restrict__ base, float* __restrict__ aggr)
{
    const int tid = threadIdx.x;
    const int n = blockIdx.x * 4 + (tid >> 6);
    const int lane = tid & 63;
    const int st = base[n];
    const int en = (n == NN_NODE - 1) ? NN_EDGE : base[n + 1];

    float mx = -1e9f;
    for (int i = st + lane; i < en; i += 64) mx = fmaxf(mx, wlog[i]);
#pragma unroll
    for (int d = 1; d < 64; d <<= 1) mx = fmaxf(mx, __shfl_xor(mx, d));

    float sm = 0.f;
    for (int i = st + lane; i < en; i += 64) sm += __expf(wlog[i] - mx);
#pragma unroll
    for (int d = 1; d < 64; d <<= 1) sm += __shfl_xor(sm, d);
    const float inv = 1.f / (sm + 1e-12f);

    float acc0 = 0.f, acc1 = 0.f;
    const f16* vp = v + (size_t)st * 128 + lane * 2;
    for (int i = st; i < en; ++i, vp += 128) {
        float attn = __expf(wlog[i] - mx) * inv;
        f16x2 vv = *(const f16x2*)vp;
        acc0 += attn * (float)vv[0];
        acc1 += attn * (float)vv[1];
    }
    float2 o; o.x = acc0; o.y = acc1;
    *(float2*)(aggr + (size_t)n * 128 + lane * 2) = o;
}

// ---- K3: node decoder (64-node tiles) ----
__global__ __launch_bounds__(256, 2) void node_kernel(
        const float* __restrict__ aggr, const f16* __restrict__ wt,
        const float* __restrict__ ub0, const float* __restrict__ ub1,
        const float* __restrict__ uw2, const float* __restrict__ ub2,
        float* __restrict__ out)
{
    __shared__ f16 ldsbuf[2 * 64 * 256];
    f16* bufA = ldsbuf;
    f16* bufB = ldsbuf + 64 * 256;
    const int tid = threadIdx.x;
    const int n0 = blockIdx.x * 64;
    {
        int row = tid >> 2, j = tid & 3;
        int n = n0 + row;
        if (n < NN_NODE) {
            const float4* src = (const float4*)(aggr + (size_t)n * 128 + j * 32);
#pragma unroll
            for (int i = 0; i < 8; ++i) {
                float4 t4 = src[i];
                int c = j * 32 + i * 4;
                bufA[swz(row, c + 0)] = (f16)t4.x;
                bufA[swz(row, c + 1)] = (f16)t4.y;
                bufA[swz(row, c + 2)] = (f16)t4.z;
                bufA[swz(row, c + 3)] = (f16)t4.w;
            }
        } else {
#pragma unroll
            for (int i = 0; i < 32; ++i) bufA[swz(row, j * 32 + i)] = (f16)0.f;
        }
    }
    __syncthreads();
    mfma_layer_basic<128, 256>(bufA, 0, wt + WT_UW0, ub0, bufB, 0, tid); __syncthreads();
    mfma_layer_basic<256, 256>(bufB, 0, wt + WT_UW1, ub1, bufA, 0, tid); __syncthreads();
    {
        int e = tid >> 2, part = tid & 3;
        float sum = 0.f;
        for (int c = part * 64; c < part * 64 + 64; ++c)
            sum += (float)bufA[swz(e, c)] * uw2[c];
        sum += __shfl_down(sum, 2);
        sum += __shfl_down(sum, 1);
        int n = n0 + e;
        if (part == 0 && n < NN_NODE) out[n] = sum + ub2[0];
    }
}

extern "C" void kernel_launch(void* const* d_in, const int* in_sizes, int n_in,
                              void* d_out, int out_size, void* d_ws, size_t ws_size,
                              hipStream_t stream)
{
    const float* nodes     = (const float*)d_in[0];
    const float* edges     = (const float*)d_in[1];
    const int*   senders   = (const int*)d_in[2];
    const int*   receivers = (const int*)d_in[3];
    const float* mw0 = (const float*)d_in[4];  const float* mb0 = (const float*)d_in[5];
    const float* mw1 = (const float*)d_in[6];  const float* mb1 = (const float*)d_in[7];
    const float* mw2 = (const float*)d_in[8];  const float* mb2 = (const float*)d_in[9];
    const float* aw0 = (const float*)d_in[10]; const float* ab0 = (const float*)d_in[11];
    const float* aw1 = (const float*)d_in[12]; const float* ab1 = (const float*)d_in[13];
    const float* aw2 = (const float*)d_in[14]; const float* ab2 = (const float*)d_in[15];
    const float* vw0 = (const float*)d_in[16]; const float* vb0 = (const float*)d_in[17];
    const float* vw1 = (const float*)d_in[18]; const float* vb1 = (const float*)d_in[19];
    const float* uw0 = (const float*)d_in[20]; const float* ub0 = (const float*)d_in[21];
    const float* uw1 = (const float*)d_in[22]; const float* ub1 = (const float*)d_in[23];
    const float* uw2 = (const float*)d_in[24]; const float* ub2 = (const float*)d_in[25];

    char* ws = (char*)d_ws;
    f16*   wt   = (f16*)ws;
    f16*   vbuf = (f16*)(ws + V_OFF);
    float* wlog = (float*)(ws + WL_OFF);
    int*   cnt  = (int*)(ws + CNT_OFF);
    int*   base = (int*)(ws + BASE_OFF);
    float* aggr = (float*)(ws + AGGR_OFF);
    float* out  = (float*)d_out;

    hipMemsetAsync(cnt, 0, NN_NODE * sizeof(int), stream);

    WSegs segs = {{
        { mw0,  10, 256,  32, WT_MW0 },
        { mw1, 256, 256, 256, WT_MW1 },
        { mw2, 256, 128, 256, WT_MW2 },
        { aw0, 128, 128, 128, WT_AW0 },
        { aw1, 128, 128, 128, WT_AW1 },
        { vw0, 128, 256, 128, WT_VW0 },
        { vw1, 256, 128, 256, WT_VW1 },
        { uw0, 128, 256, 128, WT_UW0 },
        { uw1, 256, 256, 256, WT_UW1 },
    }};
    prep_kernel<<<(WT_TOTAL + 255) / 256, 256, 0, stream>>>(segs, wt);

    hist_kernel<<<NN_EDGE / 256, 256, 0, stream>>>(receivers, cnt);
    scan_kernel<<<1, 1024, 0, stream>>>(cnt, base);

    edge_kernel<<<NN_EDGE / 64, 256, 0, stream>>>(nodes, edges, senders, receivers, wt,
        mb0, mb1, mb2, ab0, ab1, aw2, ab2, vb0, vb1, vbuf, wlog, cnt);

    aggregate_kernel<<<NN_NODE / 4, 256, 0, stream>>>(wlog, vbuf, base, aggr);

    node_kernel<<<(NN_NODE + 63) / 64, 256, 0, stream>>>(aggr, wt, ub0, ub1, uw2, ub2, out);
}